// Round 1
// baseline (1166.298 us; speedup 1.0000x reference)
//
#include <hip/hip_runtime.h>
#include <cstdint>

// Problem constants
#define M_TOK 32768   // B*S
#define BERT  768
#define HID   512
#define LAT   128
#define NV    4096
#define NK    100
#define VOCAB 30522
#define NB    128     // batch B

// ---------------------------------------------------------------------------
// Tiled f32 GEMM: C[M,N] = A[M,K] @ W[K,N] + bias, optional ReLU.
// 64x64 tile, BK=16, 256 threads, 4x4 microtile per thread.
// Requires M%64==0, N%64==0, K%16==0 (true for all our shapes).
// ---------------------------------------------------------------------------
template<bool RELU>
__global__ __launch_bounds__(256) void gemm_bias(
    const float* __restrict__ A, const float* __restrict__ W,
    const float* __restrict__ bias, float* __restrict__ C,
    int M, int N, int K)
{
    __shared__ float As[16][65];   // transposed A tile, +1 pad
    __shared__ float Ws[16][64];

    const int tid = threadIdx.x;
    const int bm = blockIdx.y * 64;
    const int bn = blockIdx.x * 64;
    const int tx = tid & 15, ty = tid >> 4;
    const int arow = tid >> 2, akk = (tid & 3) * 4;   // A tile: 64 rows x 16 k
    const int wk = tid >> 4, wn = (tid & 15) * 4;     // W tile: 16 k x 64 n

    float acc[4][4] = {};

    for (int k0 = 0; k0 < K; k0 += 16) {
        float4 av = *(const float4*)(A + (size_t)(bm + arow) * K + k0 + akk);
        float4 wv = *(const float4*)(W + (size_t)(k0 + wk) * N + bn + wn);
        As[akk + 0][arow] = av.x;
        As[akk + 1][arow] = av.y;
        As[akk + 2][arow] = av.z;
        As[akk + 3][arow] = av.w;
        *(float4*)&Ws[wk][wn] = wv;
        __syncthreads();
#pragma unroll
        for (int k = 0; k < 16; ++k) {
            float a[4], b[4];
#pragma unroll
            for (int i = 0; i < 4; ++i) a[i] = As[k][ty * 4 + i];
#pragma unroll
            for (int j = 0; j < 4; ++j) b[j] = Ws[k][tx * 4 + j];
#pragma unroll
            for (int i = 0; i < 4; ++i)
#pragma unroll
                for (int j = 0; j < 4; ++j)
                    acc[i][j] += a[i] * b[j];
        }
        __syncthreads();
    }

#pragma unroll
    for (int i = 0; i < 4; ++i) {
        int r = bm + ty * 4 + i;
        int c = bn + tx * 4;
        float4 bv = *(const float4*)(bias + c);
        float4 o;
        o.x = acc[i][0] + bv.x;
        o.y = acc[i][1] + bv.y;
        o.z = acc[i][2] + bv.z;
        o.w = acc[i][3] + bv.w;
        if (RELU) {
            o.x = fmaxf(o.x, 0.f); o.y = fmaxf(o.y, 0.f);
            o.z = fmaxf(o.z, 0.f); o.w = fmaxf(o.w, 0.f);
        }
        *(float4*)(C + (size_t)r * N + c) = o;
    }
}

// ---------------------------------------------------------------------------
// Row L2-normalize, rows of length 128. One wave (64 lanes) per row.
// ---------------------------------------------------------------------------
__global__ __launch_bounds__(64) void rownorm128(const float* __restrict__ in,
                                                 float* __restrict__ out)
{
    int row = blockIdx.x;
    int l = threadIdx.x;
    const float* p = in + (size_t)row * 128;
    float v0 = p[l], v1 = p[l + 64];
    float s = v0 * v0 + v1 * v1;
#pragma unroll
    for (int o = 32; o > 0; o >>= 1) s += __shfl_xor(s, o, 64);
    float inv = 1.0f / sqrtf(s);
    float* q = out + (size_t)row * 128;
    q[l] = v0 * inv;
    q[l + 64] = v1 * inv;
}

// ---------------------------------------------------------------------------
// segment_sum scatter: one block (128 thr) per token row.
// ---------------------------------------------------------------------------
__global__ __launch_bounds__(128) void seg_scatter(
    const float* __restrict__ z, const int* __restrict__ ids,
    float* __restrict__ seg, float* __restrict__ freq)
{
    int row = blockIdx.x;
    int l = threadIdx.x;
    int id = ids[row];
    atomicAdd(&seg[(size_t)id * 128 + l], z[(size_t)row * 128 + l]);
    if (l == 0) atomicAdd(&freq[id], 1.0f);
}

// ---------------------------------------------------------------------------
// avg = seg / max(freq,1) -> d_out avg chunk
// ---------------------------------------------------------------------------
__global__ __launch_bounds__(128) void avg_kernel(
    const float* __restrict__ seg, const float* __restrict__ freq,
    float* __restrict__ avg)
{
    int i = blockIdx.x;
    int l = threadIdx.x;
    float f = fmaxf(freq[i], 1.0f);
    avg[(size_t)i * 128 + l] = seg[(size_t)i * 128 + l] / f;
}

// ---------------------------------------------------------------------------
// argmax over logits = avg @ cn.T (softmax monotone -> same argmax).
// One block (128 thr) per vocab row; threads 0..99 each compute one dot.
// ---------------------------------------------------------------------------
__global__ __launch_bounds__(128) void argmax_kernel(
    const float* __restrict__ avg, const float* __restrict__ cn,
    int* __restrict__ cids, float* __restrict__ cids_f)
{
    __shared__ float arow[128];
    __shared__ float lg[NK];
    int row = blockIdx.x;
    int t = threadIdx.x;
    arow[t] = avg[(size_t)row * 128 + t];
    __syncthreads();
    if (t < NK) {
        float d = 0.f;
        const float* c = cn + (size_t)t * 128;
#pragma unroll 8
        for (int i = 0; i < 128; ++i) d += arow[i] * c[i];
        lg[t] = d;
    }
    __syncthreads();
    if (t == 0) {
        float best = lg[0];
        int bi = 0;
        for (int k = 1; k < NK; ++k) {
            if (lg[k] > best) { best = lg[k]; bi = k; }  // first-occurrence ties
        }
        cids[row] = bi;
        cids_f[row] = (float)bi;
    }
}

// ---------------------------------------------------------------------------
// Build 128-bit column masks from bow (nz = bow[:, :V] != 0) + popcounts.
// ---------------------------------------------------------------------------
__global__ __launch_bounds__(256) void build_masks(
    const float* __restrict__ bow, unsigned long long* __restrict__ masks,
    float* __restrict__ cnt)
{
    int j = blockIdx.x * 256 + threadIdx.x;
    if (j >= NV) return;
    unsigned long long m0 = 0, m1 = 0;
    for (int b = 0; b < 64; ++b)
        if (bow[(size_t)b * VOCAB + j] != 0.f) m0 |= 1ull << b;
    for (int b = 0; b < 64; ++b)
        if (bow[(size_t)(b + 64) * VOCAB + j] != 0.f) m1 |= 1ull << b;
    masks[2 * j] = m0;
    masks[2 * j + 1] = m1;
    cnt[j] = (float)(__popcll(m0) + __popcll(m1));
}

// ---------------------------------------------------------------------------
// co[i][j] = p_ij/(p_i p_j) = B * cnt_ij / (cnt_i * cnt_j), cnt_ij via popcount.
// grid (NV/256, NV/64); each thread owns one j, loops 64 i's.
// ---------------------------------------------------------------------------
__global__ __launch_bounds__(256) void co_kernel(
    const unsigned long long* __restrict__ masks, const float* __restrict__ cnt,
    float* __restrict__ co)
{
    int j = blockIdx.x * 256 + threadIdx.x;
    unsigned long long m0 = masks[2 * j], m1 = masks[2 * j + 1];
    float cj = cnt[j];
    int ibase = blockIdx.y * 64;
    for (int ii = 0; ii < 64; ++ii) {
        int i = ibase + ii;
        unsigned long long a0 = masks[2 * i], a1 = masks[2 * i + 1];
        float ci = cnt[i];
        float c = (float)(__popcll(a0 & m0) + __popcll(a1 & m1));
        co[(size_t)i * NV + j] = (float)NB * c / (ci * cj);
    }
}

// ---------------------------------------------------------------------------
// Closed-form cluster scan. Invalid items are no-ops. For cluster k's valid
// items (ascending vocab order), eta_j = w_ij / (counts[k]+j+1), and
//   c_new = (prod (1-eta)) * c0 + sum_j [ eta_j * prod_{l>j}(1-eta_l) ] avg_ij
// One block of 128 threads per cluster.
// ---------------------------------------------------------------------------
__global__ __launch_bounds__(128) void cluster_scan(
    const float* __restrict__ avg, const int* __restrict__ cids,
    const float* __restrict__ freq, const float* __restrict__ vw,
    const float* __restrict__ centers, const float* __restrict__ counts,
    float* __restrict__ out_centers)
{
    __shared__ int list[NV];
    __shared__ float coef[NV];
    __shared__ int tcnt[128];
    __shared__ int tot;
    __shared__ float Ptot;

    int k = blockIdx.x;
    int t = threadIdx.x;

    // gather matching valid items in ascending order
    int base = t * (NV / 128);
    int c = 0;
    for (int s = 0; s < NV / 128; ++s) {
        int i = base + s;
        if (cids[i] == k && freq[i] > 0.f) c++;
    }
    tcnt[t] = c;
    __syncthreads();
    if (t == 0) {
        int run = 0;
        for (int x = 0; x < 128; ++x) { int v = tcnt[x]; tcnt[x] = run; run += v; }
        tot = run;
    }
    __syncthreads();
    int off = tcnt[t];
    for (int s = 0; s < NV / 128; ++s) {
        int i = base + s;
        if (cids[i] == k && freq[i] > 0.f) list[off++] = i;
    }
    __syncthreads();
    int m = tot;

    // etas (parallel), then suffix products (serial by t0, m ~ 41 expected)
    float c0 = counts[k];
    for (int j = t; j < m; j += 128)
        coef[j] = vw[list[j]] / (c0 + (float)(j + 1));
    __syncthreads();
    if (t == 0) {
        float suf = 1.f;
        for (int j = m - 1; j >= 0; --j) {
            float e = coef[j];
            coef[j] = e * suf;
            suf *= (1.f - e);
        }
        Ptot = suf;
    }
    __syncthreads();

    float accv = Ptot * centers[(size_t)k * 128 + t];
    for (int j = 0; j < m; ++j)
        accv += coef[j] * avg[(size_t)list[j] * 128 + t];
    out_centers[(size_t)k * 128 + t] = accv;
}

// ---------------------------------------------------------------------------
// Normalize centers rows -> cn
// ---------------------------------------------------------------------------
__global__ __launch_bounds__(64) void cn_norm(const float* __restrict__ centers,
                                              float* __restrict__ cn)
{
    int row = blockIdx.x;
    int l = threadIdx.x;
    const float* p = centers + (size_t)row * 128;
    float v0 = p[l], v1 = p[l + 64];
    float s = v0 * v0 + v1 * v1;
#pragma unroll
    for (int o = 32; o > 0; o >>= 1) s += __shfl_xor(s, o, 64);
    float inv = 1.0f / sqrtf(s);
    cn[(size_t)row * 128 + l] = v0 * inv;
    cn[(size_t)row * 128 + l + 64] = v1 * inv;
}

// ---------------------------------------------------------------------------
extern "C" void kernel_launch(void* const* d_in, const int* in_sizes, int n_in,
                              void* d_out, int out_size, void* d_ws, size_t ws_size,
                              hipStream_t stream)
{
    const int*   input_ids = (const int*)d_in[0];
    const float* token_embs = (const float*)d_in[3];
    const float* bow       = (const float*)d_in[4];
    const float* enc_w1    = (const float*)d_in[5];
    const float* enc_b1    = (const float*)d_in[6];
    const float* enc_w2    = (const float*)d_in[7];
    const float* enc_b2    = (const float*)d_in[8];
    const float* dec_w1    = (const float*)d_in[9];
    const float* dec_b1    = (const float*)d_in[10];
    const float* dec_w2    = (const float*)d_in[11];
    const float* dec_b2    = (const float*)d_in[12];
    const float* centers   = (const float*)d_in[13];
    const float* counts    = (const float*)d_in[14];
    const float* vocab_w   = (const float*)d_in[15];

    float* out = (float*)d_out;
    // output chunk offsets (reference return order)
    const size_t OFF_CO  = 0;                       // 4096*4096
    const size_t OFF_REC = 16777216;                // 32768*768
    const size_t OFF_AVG = OFF_REC + 25165824;      // 4096*128
    const size_t OFF_CID = OFF_AVG + 524288;        // 4096
    const size_t OFF_NC  = OFF_CID + 4096;          // 100*128

    // workspace layout (floats)
    float* h    = (float*)d_ws;                     // 32768*512 (reused as hr)
    float* z    = h + (size_t)M_TOK * HID;          // 32768*128
    float* seg  = z + (size_t)M_TOK * LAT;          // 4096*128
    float* freq = seg + (size_t)NV * LAT;           // 4096
    float* cn   = freq + NV;                        // 100*128
    float* cntv = cn + (size_t)NK * LAT;            // 4096
    int*   cids = (int*)(cntv + NV);                // 4096
    unsigned long long* masks = (unsigned long long*)(cids + NV); // 4096*2

    // zero the atomic targets (ws is poisoned 0xAA before every launch)
    hipMemsetAsync(seg, 0, (size_t)(NV * LAT + NV) * sizeof(float), stream);

    // encoder
    gemm_bias<true ><<<dim3(HID / 64, M_TOK / 64), 256, 0, stream>>>(
        token_embs, enc_w1, enc_b1, h, M_TOK, HID, BERT);
    gemm_bias<false><<<dim3(LAT / 64, M_TOK / 64), 256, 0, stream>>>(
        h, enc_w2, enc_b2, z, M_TOK, LAT, HID);
    rownorm128<<<M_TOK, 64, 0, stream>>>(z, z);

    // decoder (reuse h as hidden buffer)
    gemm_bias<true ><<<dim3(HID / 64, M_TOK / 64), 256, 0, stream>>>(
        z, dec_w1, dec_b1, h, M_TOK, HID, LAT);
    gemm_bias<false><<<dim3(BERT / 64, M_TOK / 64), 256, 0, stream>>>(
        h, dec_w2, dec_b2, out + OFF_REC, M_TOK, BERT, HID);

    // segment mean
    seg_scatter<<<M_TOK, 128, 0, stream>>>(z, input_ids, seg, freq);
    avg_kernel<<<NV, 128, 0, stream>>>(seg, freq, out + OFF_AVG);

    // cluster assignment
    cn_norm<<<NK, 64, 0, stream>>>(centers, cn);
    argmax_kernel<<<NV, 128, 0, stream>>>(out + OFF_AVG, cn, cids, out + OFF_CID);

    // co-occurrence matrix
    build_masks<<<NV / 256, 256, 0, stream>>>(bow, masks, cntv);
    co_kernel<<<dim3(NV / 256, NV / 64), 256, 0, stream>>>(masks, cntv, out + OFF_CO);

    // online center update (closed form)
    cluster_scan<<<NK, 128, 0, stream>>>(out + OFF_AVG, cids, freq, vocab_w,
                                         centers, counts, out + OFF_NC);
}

// Round 2
// 1052.567 us; speedup vs baseline: 1.1081x; 1.1081x over previous
//
#include <hip/hip_runtime.h>
#include <cstdint>

// Problem constants
#define M_TOK 32768   // B*S
#define BERT  768
#define HID   512
#define LAT   128
#define NV    4096
#define NK    100
#define VOCAB 30522
#define NB    128     // batch B

// ---------------------------------------------------------------------------
// Tiled f32 GEMM: C[M,N] = A[M,K] @ W[K,N] + bias, optional ReLU.
// 128x128 tile, BK=16, 256 threads, 8x8 microtile per thread (split 2x2 of
// 4x4 at offsets {0,64} so all LDS reads are <=2-way bank aliased == free).
// Requires M%128==0, N%128==0, K%16==0 (true for all our shapes).
// ---------------------------------------------------------------------------
template<bool RELU>
__global__ __launch_bounds__(256) void gemm_bias(
    const float* __restrict__ A, const float* __restrict__ W,
    const float* __restrict__ bias, float* __restrict__ C,
    int M, int N, int K)
{
    __shared__ float As[16][132];   // [k][m], +4 pad: store conflicts 2-way, 16B aligned
    __shared__ float Ws[16][128];   // [k][n]

    const int tid = threadIdx.x;
    const int bm = blockIdx.y * 128;
    const int bn = blockIdx.x * 128;
    const int tx = tid & 15, ty = tid >> 4;

    // A staging: thread loads rows {ar, ar+64}, k-chunk ak..ak+3
    const int ar = tid >> 2;          // 0..63
    const int ak = (tid & 3) * 4;     // 0,4,8,12
    // W staging: thread loads rows {wr, wr+8}, col-chunk wc..wc+3
    const int wr = tid >> 5;          // 0..7
    const int wc = (tid & 31) * 4;    // 0..124

    const float* Ap0 = A + (size_t)(bm + ar) * K + ak;
    const float* Ap1 = A + (size_t)(bm + ar + 64) * K + ak;
    const float* Wp0 = W + (size_t)wr * N + bn + wc;
    const float* Wp1 = W + (size_t)(wr + 8) * N + bn + wc;

    float acc[8][8] = {};

    for (int k0 = 0; k0 < K; k0 += 16) {
        float4 av0 = *(const float4*)(Ap0 + k0);
        float4 av1 = *(const float4*)(Ap1 + k0);
        float4 wv0 = *(const float4*)(Wp0 + (size_t)k0 * N);
        float4 wv1 = *(const float4*)(Wp1 + (size_t)k0 * N);
        __syncthreads();   // previous iteration's reads complete
        As[ak + 0][ar] = av0.x;  As[ak + 1][ar] = av0.y;
        As[ak + 2][ar] = av0.z;  As[ak + 3][ar] = av0.w;
        As[ak + 0][ar + 64] = av1.x;  As[ak + 1][ar + 64] = av1.y;
        As[ak + 2][ar + 64] = av1.z;  As[ak + 3][ar + 64] = av1.w;
        *(float4*)&Ws[wr][wc] = wv0;
        *(float4*)&Ws[wr + 8][wc] = wv1;
        __syncthreads();
#pragma unroll
        for (int k = 0; k < 16; ++k) {
            float a[8], b[8];
            *(float4*)&a[0] = *(const float4*)&As[k][ty * 4];
            *(float4*)&a[4] = *(const float4*)&As[k][64 + ty * 4];
            *(float4*)&b[0] = *(const float4*)&Ws[k][tx * 4];
            *(float4*)&b[4] = *(const float4*)&Ws[k][64 + tx * 4];
#pragma unroll
            for (int i = 0; i < 8; ++i)
#pragma unroll
                for (int j = 0; j < 8; ++j)
                    acc[i][j] += a[i] * b[j];
        }
    }

#pragma unroll
    for (int ib = 0; ib < 2; ++ib) {
#pragma unroll
        for (int i = 0; i < 4; ++i) {
            int r = bm + ib * 64 + ty * 4 + i;
#pragma unroll
            for (int jb = 0; jb < 2; ++jb) {
                int c = bn + jb * 64 + tx * 4;
                float4 bv = *(const float4*)(bias + c);
                float4 o;
                o.x = acc[ib * 4 + i][jb * 4 + 0] + bv.x;
                o.y = acc[ib * 4 + i][jb * 4 + 1] + bv.y;
                o.z = acc[ib * 4 + i][jb * 4 + 2] + bv.z;
                o.w = acc[ib * 4 + i][jb * 4 + 3] + bv.w;
                if (RELU) {
                    o.x = fmaxf(o.x, 0.f); o.y = fmaxf(o.y, 0.f);
                    o.z = fmaxf(o.z, 0.f); o.w = fmaxf(o.w, 0.f);
                }
                *(float4*)(C + (size_t)r * N + c) = o;
            }
        }
    }
}

// ---------------------------------------------------------------------------
// Row L2-normalize, rows of length 128. One wave (64 lanes) per row.
// ---------------------------------------------------------------------------
__global__ __launch_bounds__(64) void rownorm128(const float* __restrict__ in,
                                                 float* __restrict__ out)
{
    int row = blockIdx.x;
    int l = threadIdx.x;
    const float* p = in + (size_t)row * 128;
    float v0 = p[l], v1 = p[l + 64];
    float s = v0 * v0 + v1 * v1;
#pragma unroll
    for (int o = 32; o > 0; o >>= 1) s += __shfl_xor(s, o, 64);
    float inv = 1.0f / sqrtf(s);
    float* q = out + (size_t)row * 128;
    q[l] = v0 * inv;
    q[l + 64] = v1 * inv;
}

// ---------------------------------------------------------------------------
// segment_sum scatter: one block (128 thr) per token row.
// ---------------------------------------------------------------------------
__global__ __launch_bounds__(128) void seg_scatter(
    const float* __restrict__ z, const int* __restrict__ ids,
    float* __restrict__ seg, float* __restrict__ freq)
{
    int row = blockIdx.x;
    int l = threadIdx.x;
    int id = ids[row];
    atomicAdd(&seg[(size_t)id * 128 + l], z[(size_t)row * 128 + l]);
    if (l == 0) atomicAdd(&freq[id], 1.0f);
}

// ---------------------------------------------------------------------------
// avg = seg / max(freq,1) -> d_out avg chunk
// ---------------------------------------------------------------------------
__global__ __launch_bounds__(128) void avg_kernel(
    const float* __restrict__ seg, const float* __restrict__ freq,
    float* __restrict__ avg)
{
    int i = blockIdx.x;
    int l = threadIdx.x;
    float f = fmaxf(freq[i], 1.0f);
    avg[(size_t)i * 128 + l] = seg[(size_t)i * 128 + l] / f;
}

// ---------------------------------------------------------------------------
// argmax over logits = avg @ cn.T (softmax monotone -> same argmax).
// One block (128 thr) per vocab row; threads 0..99 each compute one dot.
// ---------------------------------------------------------------------------
__global__ __launch_bounds__(128) void argmax_kernel(
    const float* __restrict__ avg, const float* __restrict__ cn,
    int* __restrict__ cids, float* __restrict__ cids_f)
{
    __shared__ float arow[128];
    __shared__ float lg[NK];
    int row = blockIdx.x;
    int t = threadIdx.x;
    arow[t] = avg[(size_t)row * 128 + t];
    __syncthreads();
    if (t < NK) {
        float d = 0.f;
        const float* c = cn + (size_t)t * 128;
#pragma unroll 8
        for (int i = 0; i < 128; ++i) d += arow[i] * c[i];
        lg[t] = d;
    }
    __syncthreads();
    if (t == 0) {
        float best = lg[0];
        int bi = 0;
        for (int k = 1; k < NK; ++k) {
            if (lg[k] > best) { best = lg[k]; bi = k; }  // first-occurrence ties
        }
        cids[row] = bi;
        cids_f[row] = (float)bi;
    }
}

// ---------------------------------------------------------------------------
// Build 128-bit column masks from bow (nz = bow[:, :V] != 0) + popcounts.
// ---------------------------------------------------------------------------
__global__ __launch_bounds__(256) void build_masks(
    const float* __restrict__ bow, unsigned long long* __restrict__ masks,
    float* __restrict__ cnt)
{
    int j = blockIdx.x * 256 + threadIdx.x;
    if (j >= NV) return;
    unsigned long long m0 = 0, m1 = 0;
    for (int b = 0; b < 64; ++b)
        if (bow[(size_t)b * VOCAB + j] != 0.f) m0 |= 1ull << b;
    for (int b = 0; b < 64; ++b)
        if (bow[(size_t)(b + 64) * VOCAB + j] != 0.f) m1 |= 1ull << b;
    masks[2 * j] = m0;
    masks[2 * j + 1] = m1;
    cnt[j] = (float)(__popcll(m0) + __popcll(m1));
}

// ---------------------------------------------------------------------------
// co[i][j] = p_ij/(p_i p_j) = B * cnt_ij / (cnt_i * cnt_j), cnt_ij via popcount.
// grid (NV/256, NV/64); each thread owns one j, loops 64 i's.
// ---------------------------------------------------------------------------
__global__ __launch_bounds__(256) void co_kernel(
    const unsigned long long* __restrict__ masks, const float* __restrict__ cnt,
    float* __restrict__ co)
{
    int j = blockIdx.x * 256 + threadIdx.x;
    unsigned long long m0 = masks[2 * j], m1 = masks[2 * j + 1];
    float cj = cnt[j];
    int ibase = blockIdx.y * 64;
    for (int ii = 0; ii < 64; ++ii) {
        int i = ibase + ii;
        unsigned long long a0 = masks[2 * i], a1 = masks[2 * i + 1];
        float ci = cnt[i];
        float c = (float)(__popcll(a0 & m0) + __popcll(a1 & m1));
        co[(size_t)i * NV + j] = (float)NB * c / (ci * cj);
    }
}

// ---------------------------------------------------------------------------
// Closed-form cluster scan. Invalid items are no-ops. For cluster k's valid
// items (ascending vocab order), eta_j = w_ij / (counts[k]+j+1), and
//   c_new = (prod (1-eta)) * c0 + sum_j [ eta_j * prod_{l>j}(1-eta_l) ] avg_ij
// One block of 128 threads per cluster.
// ---------------------------------------------------------------------------
__global__ __launch_bounds__(128) void cluster_scan(
    const float* __restrict__ avg, const int* __restrict__ cids,
    const float* __restrict__ freq, const float* __restrict__ vw,
    const float* __restrict__ centers, const float* __restrict__ counts,
    float* __restrict__ out_centers)
{
    __shared__ int list[NV];
    __shared__ float coef[NV];
    __shared__ int tcnt[128];
    __shared__ int tot;
    __shared__ float Ptot;

    int k = blockIdx.x;
    int t = threadIdx.x;

    // gather matching valid items in ascending order
    int base = t * (NV / 128);
    int c = 0;
    for (int s = 0; s < NV / 128; ++s) {
        int i = base + s;
        if (cids[i] == k && freq[i] > 0.f) c++;
    }
    tcnt[t] = c;
    __syncthreads();
    if (t == 0) {
        int run = 0;
        for (int x = 0; x < 128; ++x) { int v = tcnt[x]; tcnt[x] = run; run += v; }
        tot = run;
    }
    __syncthreads();
    int off = tcnt[t];
    for (int s = 0; s < NV / 128; ++s) {
        int i = base + s;
        if (cids[i] == k && freq[i] > 0.f) list[off++] = i;
    }
    __syncthreads();
    int m = tot;

    // etas (parallel), then suffix products (serial by t0, m ~ 41 expected)
    float c0 = counts[k];
    for (int j = t; j < m; j += 128)
        coef[j] = vw[list[j]] / (c0 + (float)(j + 1));
    __syncthreads();
    if (t == 0) {
        float suf = 1.f;
        for (int j = m - 1; j >= 0; --j) {
            float e = coef[j];
            coef[j] = e * suf;
            suf *= (1.f - e);
        }
        Ptot = suf;
    }
    __syncthreads();

    float accv = Ptot * centers[(size_t)k * 128 + t];
    for (int j = 0; j < m; ++j)
        accv += coef[j] * avg[(size_t)list[j] * 128 + t];
    out_centers[(size_t)k * 128 + t] = accv;
}

// ---------------------------------------------------------------------------
// Normalize centers rows -> cn
// ---------------------------------------------------------------------------
__global__ __launch_bounds__(64) void cn_norm(const float* __restrict__ centers,
                                              float* __restrict__ cn)
{
    int row = blockIdx.x;
    int l = threadIdx.x;
    const float* p = centers + (size_t)row * 128;
    float v0 = p[l], v1 = p[l + 64];
    float s = v0 * v0 + v1 * v1;
#pragma unroll
    for (int o = 32; o > 0; o >>= 1) s += __shfl_xor(s, o, 64);
    float inv = 1.0f / sqrtf(s);
    cn[(size_t)row * 128 + l] = v0 * inv;
    cn[(size_t)row * 128 + l + 64] = v1 * inv;
}

// ---------------------------------------------------------------------------
extern "C" void kernel_launch(void* const* d_in, const int* in_sizes, int n_in,
                              void* d_out, int out_size, void* d_ws, size_t ws_size,
                              hipStream_t stream)
{
    const int*   input_ids = (const int*)d_in[0];
    const float* token_embs = (const float*)d_in[3];
    const float* bow       = (const float*)d_in[4];
    const float* enc_w1    = (const float*)d_in[5];
    const float* enc_b1    = (const float*)d_in[6];
    const float* enc_w2    = (const float*)d_in[7];
    const float* enc_b2    = (const float*)d_in[8];
    const float* dec_w1    = (const float*)d_in[9];
    const float* dec_b1    = (const float*)d_in[10];
    const float* dec_w2    = (const float*)d_in[11];
    const float* dec_b2    = (const float*)d_in[12];
    const float* centers   = (const float*)d_in[13];
    const float* counts    = (const float*)d_in[14];
    const float* vocab_w   = (const float*)d_in[15];

    float* out = (float*)d_out;
    // output chunk offsets (reference return order)
    const size_t OFF_CO  = 0;                       // 4096*4096
    const size_t OFF_REC = 16777216;                // 32768*768
    const size_t OFF_AVG = OFF_REC + 25165824;      // 4096*128
    const size_t OFF_CID = OFF_AVG + 524288;        // 4096
    const size_t OFF_NC  = OFF_CID + 4096;          // 100*128

    // workspace layout (floats)
    float* h    = (float*)d_ws;                     // 32768*512 (reused as hr)
    float* z    = h + (size_t)M_TOK * HID;          // 32768*128
    float* seg  = z + (size_t)M_TOK * LAT;          // 4096*128
    float* freq = seg + (size_t)NV * LAT;           // 4096
    float* cn   = freq + NV;                        // 100*128
    float* cntv = cn + (size_t)NK * LAT;            // 4096
    int*   cids = (int*)(cntv + NV);                // 4096
    unsigned long long* masks = (unsigned long long*)(cids + NV); // 4096*2

    // zero the atomic targets (ws is poisoned 0xAA before every launch)
    hipMemsetAsync(seg, 0, (size_t)(NV * LAT + NV) * sizeof(float), stream);

    // encoder
    gemm_bias<true ><<<dim3(HID / 128, M_TOK / 128), 256, 0, stream>>>(
        token_embs, enc_w1, enc_b1, h, M_TOK, HID, BERT);
    gemm_bias<false><<<dim3(LAT / 128, M_TOK / 128), 256, 0, stream>>>(
        h, enc_w2, enc_b2, z, M_TOK, LAT, HID);
    rownorm128<<<M_TOK, 64, 0, stream>>>(z, z);

    // decoder (reuse h as hidden buffer)
    gemm_bias<true ><<<dim3(HID / 128, M_TOK / 128), 256, 0, stream>>>(
        z, dec_w1, dec_b1, h, M_TOK, HID, LAT);
    gemm_bias<false><<<dim3(BERT / 128, M_TOK / 128), 256, 0, stream>>>(
        h, dec_w2, dec_b2, out + OFF_REC, M_TOK, BERT, HID);

    // segment mean
    seg_scatter<<<M_TOK, 128, 0, stream>>>(z, input_ids, seg, freq);
    avg_kernel<<<NV, 128, 0, stream>>>(seg, freq, out + OFF_AVG);

    // cluster assignment
    cn_norm<<<NK, 64, 0, stream>>>(centers, cn);
    argmax_kernel<<<NV, 128, 0, stream>>>(out + OFF_AVG, cn, cids, out + OFF_CID);

    // co-occurrence matrix
    build_masks<<<NV / 256, 256, 0, stream>>>(bow, masks, cntv);
    co_kernel<<<dim3(NV / 256, NV / 64), 256, 0, stream>>>(masks, cntv, out + OFF_CO);

    // online center update (closed form)
    cluster_scan<<<NK, 128, 0, stream>>>(out + OFF_AVG, cids, freq, vocab_w,
                                         centers, counts, out + OFF_NC);
}

// Round 3
// 702.376 us; speedup vs baseline: 1.6605x; 1.4986x over previous
//
#include <hip/hip_runtime.h>
#include <cstdint>

// Problem constants
#define M_TOK 32768   // B*S
#define BERT  768
#define HID   512
#define LAT   128
#define NV    4096
#define NK    100
#define VOCAB 30522
#define NB    128     // batch B

typedef short short8 __attribute__((ext_vector_type(8)));
typedef float floatx4 __attribute__((ext_vector_type(4)));
typedef unsigned short u16x4 __attribute__((ext_vector_type(4)));

// ---- bf16 split helpers (RNE, manual bit ops: no API ambiguity) -----------
__device__ __forceinline__ unsigned short f2bf(float f) {
    unsigned u = __float_as_uint(f);
    unsigned r = (u + 0x7FFFu + ((u >> 16) & 1u)) >> 16;
    return (unsigned short)r;
}
__device__ __forceinline__ float bf2f(unsigned short h) {
    return __uint_as_float((unsigned)h << 16);
}

// ---- async global->LDS, 16B per lane --------------------------------------
__device__ __forceinline__ void async16(const void* g, void* l) {
    __builtin_amdgcn_global_load_lds(
        (const __attribute__((address_space(1))) unsigned int*)g,
        (__attribute__((address_space(3))) unsigned int*)l, 16, 0, 0);
}

// ---------------------------------------------------------------------------
// Weight split+transpose: W[K][N] f32 -> Wt limbs [NL=3][N][K] bf16.
// Small matrices (<=1.5MB); L2 absorbs the scattered reads.
// ---------------------------------------------------------------------------
__global__ __launch_bounds__(256) void wsplit(
    const float* __restrict__ W, unsigned short* __restrict__ Wt,
    int K, int N)
{
    int j = blockIdx.x * 256 + threadIdx.x;     // index over [N][K]
    int total = N * K;
    if (j >= total) return;
    int n = j / K, k = j - n * K;
    float v = W[(size_t)k * N + n];
    unsigned short h = f2bf(v);
    float r = v - bf2f(h);
    unsigned short m = f2bf(r);
    float r2 = r - bf2f(m);
    unsigned short l = f2bf(r2);
    Wt[j] = h;
    Wt[(size_t)total + j] = m;
    Wt[(size_t)2 * total + j] = l;
}

// ---------------------------------------------------------------------------
// Multi-limb bf16 MFMA GEMM: C[M,N] = A(f32)[M,K] @ W[K,N] + bias, opt ReLU.
// A is split in-kernel into NL bf16 limbs; W comes pre-split/transposed as
// Wt[NL][N][K] bf16. Products with limb-order al+bl < NL:
//   NL=3 -> 6 products (~f32-exact inputs); NL=2 -> 3 products (~2^-17 rel).
// 128x128 tile, BK=32, 256 thr (4 waves, each 64x64 via 4x4 of 16x16x32).
// Layouts match m91/m97-verified mappings (A[m][k], Bt[n][k], D col=lane&15).
// ---------------------------------------------------------------------------
template<int NL, bool RELU>
__global__ __launch_bounds__(256) void gemm_mfma(
    const float* __restrict__ A, const unsigned short* __restrict__ Wt,
    const float* __restrict__ bias, float* __restrict__ C,
    int M, int N, int K)
{
    __shared__ unsigned short Ash[NL][128 * 32];
    __shared__ unsigned short Bsh[NL][128 * 32];

    const int tid  = threadIdx.x;
    const int lane = tid & 63;
    const int wave = tid >> 6;
    const int bm = blockIdx.y * 128;
    const int bn = blockIdx.x * 128;
    const int wm = (wave & 1) * 64;
    const int wn = (wave >> 1) * 64;

    // A staging: 4 rows/thread (r = ar+32i), k-chunk ak..ak+3
    const int ar = tid >> 3;          // 0..31
    const int ak = (tid & 7) * 4;     // 0,4,..28
    // B staging (global_load_lds): per limb 2 issues; row br+64i, k-off bk
    const int br = tid >> 2;          // 0..63
    const int bk = (tid & 3) * 8;     // 0,8,16,24

    floatx4 acc[4][4];
#pragma unroll
    for (int t = 0; t < 4; ++t)
#pragma unroll
        for (int u = 0; u < 4; ++u)
            acc[t][u] = (floatx4)0.0f;

    // prefetch first A tile
    float4 av[4];
#pragma unroll
    for (int i = 0; i < 4; ++i)
        av[i] = *(const float4*)(A + (size_t)(bm + ar + 32 * i) * K + ak);

    for (int k0 = 0; k0 < K; k0 += 32) {
        // split A regs -> limbs
        u16x4 ah[NL][4];
#pragma unroll
        for (int i = 0; i < 4; ++i) {
            float vv[4] = {av[i].x, av[i].y, av[i].z, av[i].w};
#pragma unroll
            for (int e = 0; e < 4; ++e) {
                float v = vv[e];
                unsigned short h = f2bf(v);
                float r = v - bf2f(h);
                unsigned short m = f2bf(r);
                ah[0][i][e] = h;
                ah[1][i][e] = m;
                if (NL == 3) {
                    float r2 = r - bf2f(m);
                    ah[2][i][e] = f2bf(r2);
                }
            }
        }
        __syncthreads();   // prior iteration's LDS reads complete
        // B: async global->LDS (after barrier: no hazard with old reads)
#pragma unroll
        for (int l = 0; l < NL; ++l) {
            const unsigned short* wp = Wt + (size_t)l * N * K;
#pragma unroll
            for (int i = 0; i < 2; ++i)
                async16(wp + (size_t)(bn + br + 64 * i) * K + k0 + bk,
                        &Bsh[l][i * 2048 + tid * 8]);
        }
        // A: ds_write limbs
#pragma unroll
        for (int l = 0; l < NL; ++l)
#pragma unroll
            for (int i = 0; i < 4; ++i)
                *(u16x4*)&Ash[l][(ar + 32 * i) * 32 + ak] = ah[l][i];
        // prefetch next A tile (latency hidden under MFMA phase)
        if (k0 + 32 < K) {
#pragma unroll
            for (int i = 0; i < 4; ++i)
                av[i] = *(const float4*)(A + (size_t)(bm + ar + 32 * i) * K + k0 + 32 + ak);
        }
        __syncthreads();   // drains vmcnt (global_load_lds) + lgkm (ds_write)

        // A fragments, all limbs
        short8 af[NL][4];
#pragma unroll
        for (int l = 0; l < NL; ++l)
#pragma unroll
            for (int t = 0; t < 4; ++t)
                af[l][t] = *(const short8*)&Ash[l][(wm + t * 16 + (lane & 15)) * 32 + (lane >> 4) * 8];

#pragma unroll
        for (int bl = 0; bl < NL; ++bl) {
            short8 bf[4];
#pragma unroll
            for (int u = 0; u < 4; ++u)
                bf[u] = *(const short8*)&Bsh[bl][(wn + u * 16 + (lane & 15)) * 32 + (lane >> 4) * 8];
#pragma unroll
            for (int al = 0; al < NL; ++al) {
                if (al + bl >= NL) continue;   // limb-product selection
#pragma unroll
                for (int t = 0; t < 4; ++t)
#pragma unroll
                    for (int u = 0; u < 4; ++u)
                        acc[t][u] = __builtin_amdgcn_mfma_f32_16x16x32_bf16(
                            af[al][t], bf[u], acc[t][u], 0, 0, 0);
            }
        }
    }

    // epilogue: D col=lane&15, row=(lane>>4)*4+reg  [m89/m91-verified]
#pragma unroll
    for (int t = 0; t < 4; ++t) {
        int row0 = bm + wm + t * 16 + (lane >> 4) * 4;
#pragma unroll
        for (int u = 0; u < 4; ++u) {
            int col = bn + wn + u * 16 + (lane & 15);
            float b = bias[col];
#pragma unroll
            for (int r = 0; r < 4; ++r) {
                float v = acc[t][u][r] + b;
                if (RELU) v = fmaxf(v, 0.f);
                C[(size_t)(row0 + r) * N + col] = v;
            }
        }
    }
}

// ---------------------------------------------------------------------------
// Row L2-normalize, rows of length 128. One wave (64 lanes) per row.
// ---------------------------------------------------------------------------
__global__ __launch_bounds__(64) void rownorm128(const float* __restrict__ in,
                                                 float* __restrict__ out)
{
    int row = blockIdx.x;
    int l = threadIdx.x;
    const float* p = in + (size_t)row * 128;
    float v0 = p[l], v1 = p[l + 64];
    float s = v0 * v0 + v1 * v1;
#pragma unroll
    for (int o = 32; o > 0; o >>= 1) s += __shfl_xor(s, o, 64);
    float inv = 1.0f / sqrtf(s);
    float* q = out + (size_t)row * 128;
    q[l] = v0 * inv;
    q[l + 64] = v1 * inv;
}

// ---------------------------------------------------------------------------
__global__ __launch_bounds__(128) void seg_scatter(
    const float* __restrict__ z, const int* __restrict__ ids,
    float* __restrict__ seg, float* __restrict__ freq)
{
    int row = blockIdx.x;
    int l = threadIdx.x;
    int id = ids[row];
    atomicAdd(&seg[(size_t)id * 128 + l], z[(size_t)row * 128 + l]);
    if (l == 0) atomicAdd(&freq[id], 1.0f);
}

// ---------------------------------------------------------------------------
__global__ __launch_bounds__(128) void avg_kernel(
    const float* __restrict__ seg, const float* __restrict__ freq,
    float* __restrict__ avg)
{
    int i = blockIdx.x;
    int l = threadIdx.x;
    float f = fmaxf(freq[i], 1.0f);
    avg[(size_t)i * 128 + l] = seg[(size_t)i * 128 + l] / f;
}

// ---------------------------------------------------------------------------
// argmax over logits = avg @ cn.T (softmax monotone -> same argmax).
// ---------------------------------------------------------------------------
__global__ __launch_bounds__(128) void argmax_kernel(
    const float* __restrict__ avg, const float* __restrict__ cn,
    int* __restrict__ cids, float* __restrict__ cids_f)
{
    __shared__ float arow[128];
    __shared__ float lg[NK];
    int row = blockIdx.x;
    int t = threadIdx.x;
    arow[t] = avg[(size_t)row * 128 + t];
    __syncthreads();
    if (t < NK) {
        float d = 0.f;
        const float* c = cn + (size_t)t * 128;
#pragma unroll 8
        for (int i = 0; i < 128; ++i) d += arow[i] * c[i];
        lg[t] = d;
    }
    __syncthreads();
    if (t == 0) {
        float best = lg[0];
        int bi = 0;
        for (int k = 1; k < NK; ++k) {
            if (lg[k] > best) { best = lg[k]; bi = k; }  // first-occurrence ties
        }
        cids[row] = bi;
        cids_f[row] = (float)bi;
    }
}

// ---------------------------------------------------------------------------
__global__ __launch_bounds__(256) void build_masks(
    const float* __restrict__ bow, unsigned long long* __restrict__ masks,
    float* __restrict__ cnt)
{
    int j = blockIdx.x * 256 + threadIdx.x;
    if (j >= NV) return;
    unsigned long long m0 = 0, m1 = 0;
    for (int b = 0; b < 64; ++b)
        if (bow[(size_t)b * VOCAB + j] != 0.f) m0 |= 1ull << b;
    for (int b = 0; b < 64; ++b)
        if (bow[(size_t)(b + 64) * VOCAB + j] != 0.f) m1 |= 1ull << b;
    masks[2 * j] = m0;
    masks[2 * j + 1] = m1;
    cnt[j] = (float)(__popcll(m0) + __popcll(m1));
}

// ---------------------------------------------------------------------------
__global__ __launch_bounds__(256) void co_kernel(
    const unsigned long long* __restrict__ masks, const float* __restrict__ cnt,
    float* __restrict__ co)
{
    int j = blockIdx.x * 256 + threadIdx.x;
    unsigned long long m0 = masks[2 * j], m1 = masks[2 * j + 1];
    float cj = cnt[j];
    int ibase = blockIdx.y * 64;
    for (int ii = 0; ii < 64; ++ii) {
        int i = ibase + ii;
        unsigned long long a0 = masks[2 * i], a1 = masks[2 * i + 1];
        float ci = cnt[i];
        float c = (float)(__popcll(a0 & m0) + __popcll(a1 & m1));
        co[(size_t)i * NV + j] = (float)NB * c / (ci * cj);
    }
}

// ---------------------------------------------------------------------------
// Closed-form cluster scan (see Round-1 derivation).
// ---------------------------------------------------------------------------
__global__ __launch_bounds__(128) void cluster_scan(
    const float* __restrict__ avg, const int* __restrict__ cids,
    const float* __restrict__ freq, const float* __restrict__ vw,
    const float* __restrict__ centers, const float* __restrict__ counts,
    float* __restrict__ out_centers)
{
    __shared__ int list[NV];
    __shared__ float coef[NV];
    __shared__ int tcnt[128];
    __shared__ int tot;
    __shared__ float Ptot;

    int k = blockIdx.x;
    int t = threadIdx.x;

    int base = t * (NV / 128);
    int c = 0;
    for (int s = 0; s < NV / 128; ++s) {
        int i = base + s;
        if (cids[i] == k && freq[i] > 0.f) c++;
    }
    tcnt[t] = c;
    __syncthreads();
    if (t == 0) {
        int run = 0;
        for (int x = 0; x < 128; ++x) { int v = tcnt[x]; tcnt[x] = run; run += v; }
        tot = run;
    }
    __syncthreads();
    int off = tcnt[t];
    for (int s = 0; s < NV / 128; ++s) {
        int i = base + s;
        if (cids[i] == k && freq[i] > 0.f) list[off++] = i;
    }
    __syncthreads();
    int m = tot;

    float c0 = counts[k];
    for (int j = t; j < m; j += 128)
        coef[j] = vw[list[j]] / (c0 + (float)(j + 1));
    __syncthreads();
    if (t == 0) {
        float suf = 1.f;
        for (int j = m - 1; j >= 0; --j) {
            float e = coef[j];
            coef[j] = e * suf;
            suf *= (1.f - e);
        }
        Ptot = suf;
    }
    __syncthreads();

    float accv = Ptot * centers[(size_t)k * 128 + t];
    for (int j = 0; j < m; ++j)
        accv += coef[j] * avg[(size_t)list[j] * 128 + t];
    out_centers[(size_t)k * 128 + t] = accv;
}

// ---------------------------------------------------------------------------
__global__ __launch_bounds__(64) void cn_norm(const float* __restrict__ centers,
                                              float* __restrict__ cn)
{
    int row = blockIdx.x;
    int l = threadIdx.x;
    const float* p = centers + (size_t)row * 128;
    float v0 = p[l], v1 = p[l + 64];
    float s = v0 * v0 + v1 * v1;
#pragma unroll
    for (int o = 32; o > 0; o >>= 1) s += __shfl_xor(s, o, 64);
    float inv = 1.0f / sqrtf(s);
    cn[(size_t)row * 128 + l] = v0 * inv;
    cn[(size_t)row * 128 + l + 64] = v1 * inv;
}

// ---------------------------------------------------------------------------
extern "C" void kernel_launch(void* const* d_in, const int* in_sizes, int n_in,
                              void* d_out, int out_size, void* d_ws, size_t ws_size,
                              hipStream_t stream)
{
    const int*   input_ids = (const int*)d_in[0];
    const float* token_embs = (const float*)d_in[3];
    const float* bow       = (const float*)d_in[4];
    const float* enc_w1    = (const float*)d_in[5];
    const float* enc_b1    = (const float*)d_in[6];
    const float* enc_w2    = (const float*)d_in[7];
    const float* enc_b2    = (const float*)d_in[8];
    const float* dec_w1    = (const float*)d_in[9];
    const float* dec_b1    = (const float*)d_in[10];
    const float* dec_w2    = (const float*)d_in[11];
    const float* dec_b2    = (const float*)d_in[12];
    const float* centers   = (const float*)d_in[13];
    const float* counts    = (const float*)d_in[14];
    const float* vocab_w   = (const float*)d_in[15];

    float* out = (float*)d_out;
    const size_t OFF_CO  = 0;                       // 4096*4096
    const size_t OFF_REC = 16777216;                // 32768*768
    const size_t OFF_AVG = OFF_REC + 25165824;      // 4096*128
    const size_t OFF_CID = OFF_AVG + 524288;        // 4096
    const size_t OFF_NC  = OFF_CID + 4096;          // 100*128

    // workspace layout
    float* h    = (float*)d_ws;                     // 32768*512 f32 (also hr)
    float* z    = h + (size_t)M_TOK * HID;          // 32768*128
    float* seg  = z + (size_t)M_TOK * LAT;          // 4096*128
    float* freq = seg + (size_t)NV * LAT;           // 4096
    float* cn   = freq + NV;                        // 100*128
    float* cntv = cn + (size_t)NK * LAT;            // 4096
    int*   cids = (int*)(cntv + NV);                // 4096
    unsigned long long* masks = (unsigned long long*)(cids + NV); // 4096*2
    unsigned short* wt1 = (unsigned short*)(masks + 2 * NV);      // 3*512*768
    unsigned short* wt2 = wt1 + (size_t)3 * HID * BERT;           // 3*128*512
    unsigned short* wt3 = wt2 + (size_t)3 * LAT * HID;            // 3*512*128
    unsigned short* wt4 = wt3 + (size_t)3 * HID * LAT;            // 3*768*512

    // zero the atomic targets
    hipMemsetAsync(seg, 0, (size_t)(NV * LAT + NV) * sizeof(float), stream);

    // weight split+transpose (bf16 limbs, [N][K])
    wsplit<<<(BERT * HID + 255) / 256, 256, 0, stream>>>(enc_w1, wt1, BERT, HID);
    wsplit<<<(HID * LAT + 255) / 256, 256, 0, stream>>>(enc_w2, wt2, HID, LAT);
    wsplit<<<(LAT * HID + 255) / 256, 256, 0, stream>>>(dec_w1, wt3, LAT, HID);
    wsplit<<<(HID * BERT + 255) / 256, 256, 0, stream>>>(dec_w2, wt4, HID, BERT);

    // encoder (3-limb, 6 products: ~f32-exact — protects argmax downstream)
    gemm_mfma<3, true ><<<dim3(HID / 128, M_TOK / 128), 256, 0, stream>>>(
        token_embs, wt1, enc_b1, h, M_TOK, HID, BERT);
    gemm_mfma<3, false><<<dim3(LAT / 128, M_TOK / 128), 256, 0, stream>>>(
        h, wt2, enc_b2, z, M_TOK, LAT, HID);
    rownorm128<<<M_TOK, 64, 0, stream>>>(z, z);

    // decoder (2-limb, 3 products: rec only, generous threshold)
    gemm_mfma<2, true ><<<dim3(HID / 128, M_TOK / 128), 256, 0, stream>>>(
        z, wt3, dec_b1, h, M_TOK, HID, LAT);
    gemm_mfma<2, false><<<dim3(BERT / 128, M_TOK / 128), 256, 0, stream>>>(
        h, wt4, dec_b2, out + OFF_REC, M_TOK, BERT, HID);

    // segment mean
    seg_scatter<<<M_TOK, 128, 0, stream>>>(z, input_ids, seg, freq);
    avg_kernel<<<NV, 128, 0, stream>>>(seg, freq, out + OFF_AVG);

    // cluster assignment
    cn_norm<<<NK, 64, 0, stream>>>(centers, cn);
    argmax_kernel<<<NV, 128, 0, stream>>>(out + OFF_AVG, cn, cids, out + OFF_CID);

    // co-occurrence matrix
    build_masks<<<NV / 256, 256, 0, stream>>>(bow, masks, cntv);
    co_kernel<<<dim3(NV / 256, NV / 64), 256, 0, stream>>>(masks, cntv, out + OFF_CO);

    // online center update (closed form)
    cluster_scan<<<NK, 128, 0, stream>>>(out + OFF_AVG, cids, freq, vocab_w,
                                         centers, counts, out + OFF_NC);
}